// Round 2
// baseline (564.513 us; speedup 1.0000x reference)
//
#include <hip/hip_runtime.h>
#include <hip/hip_bf16.h>
#include <stdint.h>

typedef short bf16x8 __attribute__((ext_vector_type(8)));
typedef float f32x4  __attribute__((ext_vector_type(4)));

#define NNODES    32768
#define KNB       16
#define FDIM      128
#define NEG_SLOPE 0.2f
#define NBLK      512                       // persistent blocks (2 per CU)
#define ITERS     (NNODES / (4 * NBLK))     // 16 iterations x 4 nodes per block

// fp32 -> bf16 round-to-nearest-even (scalar; prep only)
static __device__ __forceinline__ unsigned short f2bf(float x) {
  union { float f; unsigned u; } v; v.f = x;
  unsigned r = v.u + 0x7fffu + ((v.u >> 16) & 1u);
  return (unsigned short)(r >> 16);
}

// packed HW conversion: 8 fp32 -> bf16x8
static __device__ __forceinline__ bf16x8 pack8(f32x4 lo, f32x4 hi) {
  union { __hip_bfloat162 h[4]; bf16x8 v; } u;
  u.h[0] = __float22bfloat162_rn(make_float2(lo[0], lo[1]));
  u.h[1] = __float22bfloat162_rn(make_float2(lo[2], lo[3]));
  u.h[2] = __float22bfloat162_rn(make_float2(hi[0], hi[1]));
  u.h[3] = __float22bfloat162_rn(make_float2(hi[2], hi[3]));
  return u.v;
}

// ---------------------------------------------------------------------------
// Prep: fragment-linear B.  BL[((kc*8 + ct)*64 + quad*16 + l16)*8 + j]
//   = B[o = ct*16 + l16][f = kc*32 + quad*8 + j],  f in [0,384) = [M1|M2|W].
// ---------------------------------------------------------------------------
static __device__ __forceinline__ void storeBL(unsigned short* BL, int ct, int l16,
                                               int col, unsigned short v) {
  const int kc = col >> 5, quad = (col >> 3) & 3, j = col & 7;
  BL[(size_t)(((kc * 8 + ct) * 64) + quad * 16 + l16) * 8 + j] = v;
}

__global__ void prep_weights(const float* __restrict__ W,
                             const float* __restrict__ Wa,
                             unsigned short* __restrict__ BL) {
  const int o = blockIdx.x;    // 0..127 output col
  const int f = threadIdx.x;   // 0..127
  const float* war = Wa + o * 256;
  float a1 = 0.f, a2 = 0.f;
  #pragma unroll 8
  for (int j = 0; j < 128; ++j) {
    float w = W[j * 128 + f];                // coalesced across threads
    a1 = fmaf(war[j], w, a1);
    a2 = fmaf(war[128 + j], w, a2);
  }
  const int ct = o >> 4, l16 = o & 15;
  storeBL(BL, ct, l16, f,       f2bf(a1));
  storeBL(BL, ct, l16, 128 + f, f2bf(a2));
  storeBL(BL, ct, l16, 256 + f, f2bf(W[o * 128 + f]));
}

// ---------------------------------------------------------------------------
// Main: 8 waves/block, wave w owns col-tile ct=w (B = 12 frags in regs).
// Per iteration: 4 nodes.  Edge A staged as PRE-PACKED MFMA FRAGMENTS in LDS
// (1KB per frag, double-XOR swizzle: writes 2-way free, reads = full-1KB
// permutation = conflict-free).  Double-buffered; loads for iter i+1 issued
// at top of iter i, consumed after compute+epilogue (~2.4k cyc slack).
// One barrier per 4 nodes.
// ---------------------------------------------------------------------------
__global__ __launch_bounds__(512, 4)
void grn_main(const float* __restrict__ nodes,
              const float* __restrict__ neighbors,
              const float* __restrict__ aspects,
              const float* __restrict__ scores,
              const unsigned short* __restrict__ BL,
              const float* __restrict__ ba,
              const float* __restrict__ bias,
              float* __restrict__ out) {
  const int tid  = threadIdx.x;
  const int lane = tid & 63;
  const int w    = tid >> 6;     // wave id == ct (output col tile)
  const int quad = lane >> 4;
  const int l16  = lane & 15;

  // LDS 72.2 KB/block (2 blocks/CU = 144 KB <= 160 KB):
  __shared__ __align__(16) unsigned short Afr[2][4][8][512];  // 64 KB frag-linear edge A
  __shared__ __align__(16) unsigned short Andl[2][4][128];    // 2 KB node vectors
  __shared__ float xp[2][4][FDIM];                            // 4 KB output transpose
  __shared__ float scl[2][4][KNB];                            // 512 B scores

  // ---- B fragments: resident in registers for the whole kernel (48 VGPR)
  bf16x8 breg[12];
  #pragma unroll
  for (int kc = 0; kc < 12; ++kc)
    breg[kc] = *(const bf16x8*)(BL + ((size_t)(kc * 8 + w) * 64 + lane) * 8);

  const float ba_c   = ba[w * 16 + l16];
  const float bias_t = bias[tid & 127];

  // ---- staging decode: thread owns A[row][seg*128 + c16*8 .. +8] per node
  const int seg = tid >> 8;            // 0: neighbors, 1: aspects
  const int row = (tid >> 4) & 15;     // edge index 0..15
  const int c16 = tid & 15;
  const float* segp = seg ? aspects : neighbors;
  const int kcw   = seg * 4 + (c16 >> 2);                    // frag this piece feeds
  const int qw    = c16 & 3;                                 // quad within frag
  const int slotw = ((qw * 16) | (row ^ (qw << 1))) ^ kcw;   // swizzled 16B slot
  const int wroff = kcw * 1024 + slotw * 16;                 // const per thread
  const int sl16  = ((quad * 16) | (l16 ^ (quad << 1))) * 16;// read-side slot base

  const int node0 = blockIdx.x * (ITERS * 4);

  f32x4 eg[4][2];   // in-flight edge fp32 (4 nodes x 8 floats)
  f32x4 nd2[2];     // in-flight node fp32 (tid<64)
  f32x4 scv;        // in-flight scores (tid<16)

  auto issue_loads = [&](int j) {
    const size_t nb0 = (size_t)node0 + (size_t)j * 4;
    #pragma unroll
    for (int m = 0; m < 4; ++m) {
      const float* src = segp + ((nb0 + m) * KNB + row) * FDIM + c16 * 8;
      eg[m][0] = *(const f32x4*)src;
      eg[m][1] = *(const f32x4*)(src + 4);
    }
    if (tid < 64) {
      const float* nsrc = nodes + (nb0 + (tid >> 4)) * FDIM + (tid & 15) * 8;
      nd2[0] = *(const f32x4*)nsrc;
      nd2[1] = *(const f32x4*)(nsrc + 4);
    }
    if (tid < 16)
      scv = *(const f32x4*)(scores + (nb0 + (tid >> 2)) * KNB + (tid & 3) * 4);
  };

  auto write_stage = [&](int b) {
    char* abase = (char*)Afr + b * 32768;
    #pragma unroll
    for (int m = 0; m < 4; ++m)
      *(bf16x8*)(abase + m * 8192 + wroff) = pack8(eg[m][0], eg[m][1]);
    if (tid < 64)
      *(bf16x8*)((char*)Andl + b * 1024 + tid * 16) = pack8(nd2[0], nd2[1]);
    if (tid < 16)
      *(f32x4*)&scl[b][tid >> 2][(tid & 3) * 4] = scv;
  };

  // ---- prologue
  issue_loads(0);
  write_stage(0);
  __syncthreads();

  for (int i = 0; i < ITERS; ++i) {
    const int buf = i & 1;
    if (i + 1 < ITERS) issue_loads(i + 1);   // in flight across compute+epilogue

    // ---- compute: 4 nodes, K=384, 4 independent acc chains interleaved
    f32x4 acc[4];
    #pragma unroll
    for (int m = 0; m < 4; ++m) acc[m] = (f32x4){0.f, 0.f, 0.f, 0.f};

    const char* ab = (const char*)Afr + buf * 32768;
    const char* nb = (const char*)Andl + buf * 1024;
    #pragma unroll
    for (int kc = 0; kc < 8; ++kc) {         // edge cols 0..255
      const int off = kc * 1024 + (sl16 ^ (kc << 4));
      #pragma unroll
      for (int m = 0; m < 4; ++m) {
        bf16x8 af = *(const bf16x8*)(ab + m * 8192 + off);
        acc[m] = __builtin_amdgcn_mfma_f32_16x16x32_bf16(af, breg[kc], acc[m], 0, 0, 0);
      }
    }
    #pragma unroll
    for (int kn = 0; kn < 4; ++kn) {         // node cols 256..383 (broadcast rows)
      const int off = (kn * 4 + quad) * 16;
      #pragma unroll
      for (int m = 0; m < 4; ++m) {
        bf16x8 af = *(const bf16x8*)(nb + m * 256 + off);
        acc[m] = __builtin_amdgcn_mfma_f32_16x16x32_bf16(af, breg[8 + kn], acc[m], 0, 0, 0);
      }
    }

    // ---- epilogue first (VALU-heavy; gives the staging vmcnt max slack)
    #pragma unroll
    for (int m = 0; m < 4; ++m) {
      f32x4 sc = *(const f32x4*)&scl[buf][m][quad * 4];
      float s = 0.f;
      #pragma unroll
      for (int r = 0; r < 4; ++r) {
        float t  = acc[m][r] + ba_c;
        float lr = t > 0.f ? t : NEG_SLOPE * t;
        s = fmaf(__expf(lr), sc[r], s);
      }
      s += __shfl_xor(s, 16);
      s += __shfl_xor(s, 32);
      if (quad == 0) xp[buf][m][w * 16 + l16] = s;
    }

    // ---- convert + write next iteration's staging, then the one barrier
    if (i + 1 < ITERS) write_stage(buf ^ 1);
    __syncthreads();

    // ---- output store (full 2KB coalesced across the block)
    {
      const int n = tid >> 7, c = tid & 127;
      float v = xp[buf][n][c] + bias_t;
      v = v > 0.f ? v : __expf(v) - 1.f;
      out[((size_t)node0 + i * 4 + n) * FDIM + c] = v;
    }
  }
}

extern "C" void kernel_launch(void* const* d_in, const int* in_sizes, int n_in,
                              void* d_out, int out_size, void* d_ws, size_t ws_size,
                              hipStream_t stream) {
  const float* nodes     = (const float*)d_in[0];
  const float* neighbors = (const float*)d_in[1];
  const float* aspects   = (const float*)d_in[2];
  const float* scores    = (const float*)d_in[3];
  const float* W         = (const float*)d_in[4];
  const float* Wa        = (const float*)d_in[5];
  const float* ba        = (const float*)d_in[6];
  const float* bias      = (const float*)d_in[7];
  unsigned short* BL     = (unsigned short*)d_ws;   // 12*8*64*8*2B = 96 KB

  prep_weights<<<128, 128, 0, stream>>>(W, Wa, BL);
  grn_main<<<NBLK, 512, 0, stream>>>(nodes, neighbors, aspects, scores,
                                     BL, ba, bias, (float*)d_out);
}